// Round 1
// baseline (3605.455 us; speedup 1.0000x reference)
//
#include <hip/hip_runtime.h>
#include <math.h>

#define EMBED 128
#define NCLS 21
#define NI_ 300
#define IMH 96
#define IMW 320
#define NPIX (IMH*IMW)
#define NQ 262144
#define NF_MAX 73728
#define INST_MAX 16
#define IH_MAX 64
#define RS32 0.17677669529663687f

// ---- SMALL region layout (4-byte units at ws base) ----
#define S_NF 0
#define S_NK 1
#define S_NINST 2
#define S_NIH 3
#define S_INVK 8      // 9 f
#define S_INVE 24     // 16 f
#define S_KIDX 64     // 300 i
#define S_SKK 400     // 300 f
#define S_MAREA 768   // 300 i
#define S_PAREA 1088  // 300 i
#define S_AREA2 1408  // 300 i
#define S_XYZ 1728    // 900 f
#define S_SELJ 2656   // 16 i
#define S_K2 2688     // 16 i
#define S_FCNT 3072   // 256 i
#define S_FOFF 3328   // 256 i
#define S_INSTQ 4096  // 16*128 f
#define S_INSTP 6144
#define S_QIN 8192
#define S_QH 10240
#define S_XI 12288
#define S_KHB 16384
#define S_VHB 18432
#define S_QKT 20480   // 64*128 f
#define S_SB 28672    // 64 f
#define S_SUMV 28928  // 64 f
#define S_WSUM 29056  // 64*128 f

#define OFF_FIDX ((size_t)1<<20)
#define OFF_INV  ((size_t)2<<20)
#define OFF_W1T  ((size_t)3<<20)
#define OFF_W2T  (((size_t)3<<20) + 512*128*4)
#define OFF_SE   ((size_t)4<<20)
#define SE_BYTES ((size_t)NF_MAX*128*4)
#define OFF_A1   (OFF_SE + SE_BYTES)
#define OFF_A2   (OFF_A1 + SE_BYTES)
#define OFF_SC   (OFF_A2 + SE_BYTES)

__global__ __launch_bounds__(256) void k_init(const float* Km, const float* Em, float* ws){
  int* iw = (int*)ws;
  for (int i = threadIdx.x; i < 4096; i += 256) iw[i] = 0;
  __syncthreads();
  if (threadIdx.x == 0){
    float* fw = ws;
    const float* K = Km;
    float A = K[4]*K[8]-K[5]*K[7];
    float B = K[5]*K[6]-K[3]*K[8];
    float C = K[3]*K[7]-K[4]*K[6];
    float det = K[0]*A + K[1]*B + K[2]*C;
    float id = 1.0f/det;
    fw[S_INVK+0] = A*id;
    fw[S_INVK+1] = (K[2]*K[7]-K[1]*K[8])*id;
    fw[S_INVK+2] = (K[1]*K[5]-K[2]*K[4])*id;
    fw[S_INVK+3] = B*id;
    fw[S_INVK+4] = (K[0]*K[8]-K[2]*K[6])*id;
    fw[S_INVK+5] = (K[2]*K[3]-K[0]*K[5])*id;
    fw[S_INVK+6] = C*id;
    fw[S_INVK+7] = (K[1]*K[6]-K[0]*K[7])*id;
    fw[S_INVK+8] = (K[0]*K[4]-K[1]*K[3])*id;
    // 4x4 Gauss-Jordan inverse of E
    float M[4][8];
    for (int r=0;r<4;r++){ for(int c=0;c<4;c++){ M[r][c]=Em[r*4+c]; M[r][4+c]=(r==c)?1.f:0.f; } }
    for (int col=0; col<4; col++){
      int piv=col; float best=fabsf(M[col][col]);
      for (int r=col+1;r<4;r++){ float v=fabsf(M[r][col]); if(v>best){best=v;piv=r;} }
      if (piv!=col){ for(int c=0;c<8;c++){ float tmp=M[col][c]; M[col][c]=M[piv][c]; M[piv][c]=tmp; } }
      float inv=1.0f/M[col][col];
      for (int c=0;c<8;c++) M[col][c]*=inv;
      for (int r=0;r<4;r++){ if(r==col) continue; float f=M[r][col]; for(int c=0;c<8;c++) M[r][c]-=f*M[col][c]; }
    }
    for (int r=0;r<4;r++) for(int c=0;c<4;c++) fw[S_INVE+r*4+c]=M[r][4+c];
  }
}

__global__ __launch_bounds__(320) void k_score(const float* logits, float* ws){
  int* iw=(int*)ws; float* fw=ws;
  __shared__ float ssc[NI_];
  __shared__ int skp[NI_];
  int t=threadIdx.x;
  if (t < NI_){
    float v[NCLS]; float mx=-1e30f;
    for (int c=0;c<NCLS;c++){
      float l=logits[t*NCLS+c];
      float sg=1.0f/(1.0f+expf(-l));
      float x=sg/0.06f;
      v[c]=x; mx=fmaxf(mx,x);
    }
    float s=0.f;
    for (int c=0;c<NCLS;c++) s += expf(v[c]-mx);
    float score=1.0f/s;     // max softmax prob
    ssc[t]=score; skp[t]=(score>0.25f)?1:0;
  }
  __syncthreads();
  if (t==0){
    int nk=0;
    for (int i=0;i<NI_;i++){ if(skp[i]){ iw[S_KIDX+nk]=i; fw[S_SKK+nk]=ssc[i]; nk++; } }
    iw[S_NK]=nk;
  }
}

__global__ __launch_bounds__(256) void k_winner(const float* pmask, const float* depth, float* ws){
  int* iw=(int*)ws; float* fw=ws;
  int p=blockIdx.x*256+threadIdx.x;
  int nk=iw[S_NK];
  float best=-1e30f; int jw=-1; float mw=0.f;
  for (int j=0;j<nk;j++){
    int gi=iw[S_KIDX+j];
    float m=1.0f/(1.0f+expf(-pmask[(size_t)gi*NPIX+p]));
    if (m>=0.5f) atomicAdd(&iw[S_PAREA+j],1);
    float wv=fw[S_SKK+j]*m;
    if (wv>best){ best=wv; jw=j; mw=m; }
  }
  if (jw>=0){
    atomicAdd(&iw[S_MAREA+jw],1);
    if (mw>=0.5f){
      atomicAdd(&iw[S_AREA2+jw],1);
      float d=depth[p];
      float gx=(float)(p%IMW)*4.0f, gy=(float)(p/IMW)*4.0f;
      float X=gx*d, Y=gy*d;
      const float* iK=fw+S_INVK; const float* iE=fw+S_INVE;
      float c0=iK[0]*X+iK[1]*Y+iK[2]*d;
      float c1=iK[3]*X+iK[4]*Y+iK[5]*d;
      float c2=iK[6]*X+iK[7]*Y+iK[8]*d;
      float wx=iE[0]*c0+iE[1]*c1+iE[2]*c2+iE[3];
      float wy=iE[4]*c0+iE[5]*c1+iE[6]*c2+iE[7];
      float wz=iE[8]*c0+iE[9]*c1+iE[10]*c2+iE[11];
      atomicAdd(&fw[S_XYZ+jw*3+0],wx);
      atomicAdd(&fw[S_XYZ+jw*3+1],wy);
      atomicAdd(&fw[S_XYZ+jw*3+2],wz);
    }
  }
}

__global__ __launch_bounds__(256) void k_sel(const float* queries, const float* instposw, const float* posw, float* ws){
  int* iw=(int*)ws; float* fw=ws;
  __shared__ int sn;
  if (threadIdx.x==0){
    int nk=iw[S_NK]; int n=0;
    for (int j=0;j<nk;j++){
      int a2=iw[S_AREA2+j];
      if (a2>0){
        float r=(float)iw[S_MAREA+j]/(float)iw[S_PAREA+j];
        if (r>=0.8f && n<INST_MAX){ iw[S_SELJ+n]=j; iw[S_K2+n]=iw[S_KIDX+j]; n++; }
      }
    }
    iw[S_NINST]=n; iw[S_NIH]=4*n; sn=n;
  }
  __syncthreads();
  int n=sn;
  for (int idx=threadIdx.x; idx<n*128; idx+=256){
    int i=idx>>7, e=idx&127;
    int j=iw[S_SELJ+i]; int gi=iw[S_K2+i];
    fw[S_INSTQ+idx]=queries[gi*128+e];
    float mp=fw[S_XYZ+j*3]*posw[e*3]+fw[S_XYZ+j*3+1]*posw[e*3+1]+fw[S_XYZ+j*3+2]*posw[e*3+2];
    fw[S_INSTP+idx]=instposw[gi*128+e]+mp;
  }
}

__global__ __launch_bounds__(256) void k_fov_count(const int* fov, float* ws){
  int* iw=(int*)ws;
  __shared__ int red[256];
  int t=threadIdx.x;
  int base=blockIdx.x*1024;
  int s=0;
  for (int k=0;k<4;k++) s += (fov[base+k*256+t]!=0)?1:0;
  red[t]=s; __syncthreads();
  for (int st=128;st>0;st>>=1){ if(t<st) red[t]+=red[t+st]; __syncthreads(); }
  if (t==0) iw[S_FCNT+blockIdx.x]=red[0];
}

__global__ void k_fov_scan(float* ws){
  int* iw=(int*)ws;
  if (threadIdx.x==0){
    int acc=0;
    for (int b=0;b<256;b++){ iw[S_FOFF+b]=acc; acc+=iw[S_FCNT+b]; }
    iw[S_NF]=(acc<NF_MAX)?acc:NF_MAX;
  }
}

__global__ __launch_bounds__(256) void k_fov_scatter(const int* fov, float* ws){
  int* iw=(int*)ws;
  int* fidx=(int*)((char*)ws+OFF_FIDX);
  int* invr=(int*)((char*)ws+OFF_INV);
  __shared__ int wsums[4];
  __shared__ int woff[4];
  __shared__ int cur;
  __shared__ int tot;
  int t=threadIdx.x; int w=t>>6; int lane=t&63;
  if (t==0) cur=iw[S_FOFF+blockIdx.x];
  __syncthreads();
  int base=blockIdx.x*1024;
  for (int k=0;k<4;k++){
    int i=base+k*256+t;
    int f=(fov[i]!=0)?1:0;
    unsigned long long m=__ballot(f);
    int rk=__popcll(m & ((lane==0)?0ull:((~0ull)>>(64-lane))));
    if (lane==0) wsums[w]=__popcll(m);
    __syncthreads();
    if (t==0){ int a=0; for(int q2=0;q2<4;q2++){ woff[q2]=a; a+=wsums[q2]; } tot=a; }
    __syncthreads();
    if (f){
      int r=cur+woff[w]+rk;
      if (r<NF_MAX){ fidx[r]=i; invr[i]=r; } else invr[i]=-1;
    } else invr[i]=-1;
    __syncthreads();
    if (t==0) cur+=tot;
    __syncthreads();
  }
}

__global__ __launch_bounds__(256) void k_se_build(const float* sew, const float* x3d, const int* fidx, float* SE, float* ws){
  int* iw=(int*)ws;
  int nf=iw[S_NF];
  int r0=blockIdx.x*64;
  if (r0>=nf) return;
  int nr=min(64,nf-r0);
  __shared__ float tile[64][129];
  __shared__ int fidxl[64];
  int t=threadIdx.x;
  if (t<64) fidxl[t]=(t<nr)? fidx[r0+t]:0;
  __syncthreads();
  for (int idx=t; idx<64*128; idx+=256){
    int v=idx>>7, e=idx&127;
    tile[v][e]=(v<nr)? sew[(size_t)fidxl[v]*128+e]:0.f;
  }
  __syncthreads();
  for (int idx=t; idx<128*64; idx+=256){
    int c=idx>>6, v=idx&63;
    if (v<nr) tile[v][c]+=x3d[(size_t)c*NQ+fidxl[v]];
  }
  __syncthreads();
  for (int idx=t; idx<64*128; idx+=256){
    int v=idx>>7, e=idx&127;
    if (v<nr) SE[(r0+v)*128+e]=tile[v][e];
  }
}

__global__ __launch_bounds__(256) void kA_prep(const float* Wq, const float* bq, const float* Wk, const float* bk, float* ws){
  int* iw=(int*)ws; float* fw=ws;
  int n=iw[S_NINST]; int nih=iw[S_NIH];
  int t=threadIdx.x;
  for (int idx=t; idx<n*128; idx+=256) fw[S_QIN+idx]=fw[S_INSTQ+idx]+fw[S_INSTP+idx];
  __syncthreads();
  for (int idx=t; idx<n*128; idx+=256){
    int i=idx>>7, e=idx&127;
    float a=bq[e];
    for (int k=0;k<128;k++) a+=fw[S_QIN+i*128+k]*Wq[e*128+k];
    fw[S_QH+idx]=a;
  }
  __syncthreads();
  for (int idx=t; idx<nih*128; idx+=256){
    int ih=idx>>7, e=idx&127;
    int i=ih>>2, h=ih&3;
    float a=0.f;
    for (int d=0;d<32;d++) a+=fw[S_QH+i*128+h*32+d]*Wk[(h*32+d)*128+e];
    fw[S_QKT+idx]=a*RS32;
  }
  for (int ih=t; ih<nih; ih+=256){
    int i=ih>>2, h=ih&3;
    float a=0.f;
    for (int d=0;d<32;d++) a+=fw[S_QH+i*128+h*32+d]*bk[h*32+d];
    fw[S_SB+ih]=a*RS32;
  }
}

__global__ __launch_bounds__(256) void kS1(const float* SE, float* SC, const float* posw, const float* org, const int* fidx, float* ws){
  int* iw=(int*)ws; float* fw=ws;
  int nf=iw[S_NF]; int nih=iw[S_NIH];
  int r0=blockIdx.x*64;
  if (r0>=nf || nih==0) return;
  int nr=min(64,nf-r0);
  __shared__ float xt[64][129];
  __shared__ float qk[IH_MAX*128];
  __shared__ float sbl[IH_MAX];
  __shared__ float pwl[384];
  __shared__ float px[64],py[64],pz[64];
  __shared__ int fidxl[64];
  int t=threadIdx.x;
  for (int i=t;i<384;i+=256) pwl[i]=posw[i];
  if (t<64) fidxl[t]=(t<nr)? fidx[r0+t]:0;
  for (int idx=t; idx<nih*128; idx+=256) qk[idx]=fw[S_QKT+idx];
  if (t<IH_MAX) sbl[t]=(t<nih)? fw[S_SB+t]:0.f;
  __syncthreads();
  if (t<64){
    int q=fidxl[t];
    int vx=q>>11, vy=(q>>4)&127, vz=q&15;
    px[t]=(vx+0.5f)*0.2f+org[0];
    py[t]=(vy+0.5f)*0.2f+org[1];
    pz[t]=(vz+0.5f)*0.2f+org[2];
  }
  __syncthreads();
  for (int idx=t; idx<64*128; idx+=256){
    int v=idx>>7, e=idx&127;
    float val=0.f;
    if (v<nr) val=SE[(r0+v)*128+e]+px[v]*pwl[e*3]+py[v]*pwl[e*3+1]+pz[v]*pwl[e*3+2];
    xt[v][e]=val;
  }
  __syncthreads();
  int tokl=t&63, base=t>>6;
  for (int ih=base; ih<nih; ih+=4){
    float a=sbl[ih];
    const float* qrow=qk+ih*128;
    for (int e=0;e<128;e++) a+=qrow[e]*xt[tokl][e];
    if (tokl<nr) SC[(size_t)ih*NF_MAX+r0+tokl]=a;
  }
}

__global__ __launch_bounds__(256) void kS2S3(float* SC, float* ws){
  int* iw=(int*)ws; float* fw=ws;
  int nih=iw[S_NIH]; int ih=blockIdx.x;
  if (ih>=nih) return;
  int nf=iw[S_NF];
  float* row=SC+(size_t)ih*NF_MAX;
  __shared__ float red[256];
  int t=threadIdx.x;
  float m=-1e30f;
  for (int j=t;j<nf;j+=256) m=fmaxf(m,row[j]);
  red[t]=m; __syncthreads();
  for (int s=128;s>0;s>>=1){ if(t<s) red[t]=fmaxf(red[t],red[t+s]); __syncthreads(); }
  m=red[0]; __syncthreads();
  float sum=0.f;
  for (int j=t;j<nf;j+=256){ float p=expf(row[j]-m); row[j]=p; sum+=p; }
  red[t]=sum; __syncthreads();
  for (int s=128;s>0;s>>=1){ if(t<s) red[t]+=red[t+s]; __syncthreads(); }
  if (t==0) fw[S_SUMV+ih]=red[0];
  if (t<128) fw[S_WSUM+ih*128+t]=0.f;
}

__global__ __launch_bounds__(256) void kS4(const float* SC, const float* SE, float* ws){
  int* iw=(int*)ws; float* fw=ws;
  int nf=iw[S_NF]; int nih=iw[S_NIH];
  if (nih==0) return;
  int t=threadIdx.x;
  int chunk=(nf+255)/256;
  int j0=blockIdx.x*chunk;
  int j1=min(nf,j0+chunk);
  if (j0>=j1) return;
  __shared__ float pt[64*64];
  int e=t&127, half=t>>7;
  float acc[32];
  #pragma unroll
  for (int r=0;r<32;r++) acc[r]=0.f;
  for (int jj=j0; jj<j1; jj+=64){
    int cnt=min(64,j1-jj);
    __syncthreads();
    for (int idx=t; idx<64*64; idx+=256){
      int ih=idx>>6, jl=idx&63;
      pt[idx]=(ih<nih && jl<cnt)? SC[(size_t)ih*NF_MAX+jj+jl]:0.f;
    }
    __syncthreads();
    for (int jl=0; jl<cnt; jl++){
      float sv=SE[(jj+jl)*128+e];
      #pragma unroll
      for (int r=0;r<32;r++) acc[r]+=pt[(half*32+r)*64+jl]*sv;
    }
  }
  #pragma unroll
  for (int r=0;r<32;r++) atomicAdd(&fw[S_WSUM+(half*32+r)*128+e], acc[r]);
}

__global__ __launch_bounds__(256) void kA_post(const float* Wv, const float* bv, const float* Wo, const float* bo,
    const float* g, const float* bb, float* ws){
  int* iw=(int*)ws; float* fw=ws;
  int n=iw[S_NINST]; int nih=iw[S_NIH];
  __shared__ float wn[IH_MAX*128];
  __shared__ float ol[INST_MAX*128];
  __shared__ float tl[INST_MAX*128];
  int t=threadIdx.x;
  for (int idx=t; idx<nih*128; idx+=256){
    int ih=idx>>7;
    wn[idx]=fw[S_WSUM+idx]/fw[S_SUMV+ih];
  }
  __syncthreads();
  for (int idx=t; idx<n*128; idx+=256){
    int i=idx>>7, f=idx&127; int h=f>>5;
    float a=bv[f];
    const float* wrow=Wv+f*128;
    const float* wv=wn+(i*4+h)*128;
    for (int e2=0;e2<128;e2++) a+=wrow[e2]*wv[e2];
    ol[idx]=a;
  }
  __syncthreads();
  for (int idx=t; idx<n*128; idx+=256){
    int i=idx>>7, e2=idx&127;
    float a=bo[e2];
    const float* orow=ol+i*128;
    const float* wrow=Wo+e2*128;
    for (int f2=0;f2<128;f2++) a+=orow[f2]*wrow[f2];
    tl[idx]=a+fw[S_QIN+idx];
  }
  __syncthreads();
  int w=t>>6, lane=t&63;
  for (int i=w;i<n;i+=4){
    float v0=tl[i*128+lane], v1=tl[i*128+64+lane];
    float s=v0+v1;
    for (int o=32;o>0;o>>=1) s+=__shfl_xor(s,o);
    float mu=s*(1.f/128.f);
    float d0=v0-mu, d1=v1-mu;
    float vv=d0*d0+d1*d1;
    for (int o=32;o>0;o>>=1) vv+=__shfl_xor(vv,o);
    float rsv=rsqrtf(vv*(1.f/128.f)+1e-5f);
    fw[S_XI+i*128+lane]=d0*rsv*g[lane]+bb[lane];
    fw[S_XI+i*128+64+lane]=d1*rsv*g[64+lane]+bb[64+lane];
  }
}

__global__ __launch_bounds__(256) void kA_ffn(const float* W1, const float* b1, const float* W2, const float* b2,
    const float* g, const float* bb, float* ws){
  int* iw=(int*)ws; float* fw=ws;
  int n=iw[S_NINST];
  int i=blockIdx.x;
  if (i>=n) return;
  __shared__ float xl[128];
  __shared__ float hid[512];
  __shared__ float yv[128];
  int t=threadIdx.x;
  if (t<128) xl[t]=fw[S_XI+i*128+t];
  __syncthreads();
  for (int d=t; d<512; d+=256){
    float a=b1[d];
    const float* wr=W1+d*128;
    for (int k=0;k<128;k++) a+=wr[k]*xl[k];
    hid[d]=fmaxf(a,0.f);
  }
  __syncthreads();
  if (t<128){
    float a=b2[t];
    const float* wr=W2+(size_t)t*512;
    for (int d=0;d<512;d++) a+=wr[d]*hid[d];
    yv[t]=a+xl[t];
  }
  __syncthreads();
  if (t<64){
    float v0=yv[t], v1=yv[t+64];
    float s=v0+v1;
    for (int o=32;o>0;o>>=1) s+=__shfl_xor(s,o);
    float mu=s*(1.f/128.f);
    float d0=v0-mu, d1=v1-mu;
    float vv=d0*d0+d1*d1;
    for (int o=32;o>0;o>>=1) vv+=__shfl_xor(vv,o);
    float rsv=rsqrtf(vv*(1.f/128.f)+1e-5f);
    fw[S_INSTQ+i*128+t]=d0*rsv*g[t]+bb[t];
    fw[S_INSTQ+i*128+64+t]=d1*rsv*g[64+t]+bb[64+t];
  }
}

__global__ __launch_bounds__(256) void kA_kv(const float* Wk2, const float* bk2, const float* Wv2, const float* bv2, float* ws){
  int* iw=(int*)ws; float* fw=ws;
  int n=iw[S_NINST];
  int t=threadIdx.x;
  for (int idx=t; idx<n*128; idx+=256){
    int i=idx>>7, e=idx&127;
    float ak=bk2[e], av=bv2[e];
    const float* wk=Wk2+e*128;
    const float* wv=Wv2+e*128;
    for (int k=0;k<128;k++){
      float qv=fw[S_INSTQ+i*128+k];
      float qp=qv+fw[S_INSTP+i*128+k];
      ak+=qp*wk[k];
      av+=qv*wv[k];
    }
    fw[S_KHB+idx]=ak; fw[S_VHB+idx]=av;
  }
}

__global__ __launch_bounds__(256) void kGEMM(const float* A, float* C, const float* W, const float* bias,
    int mode_in, int mode_out, const float* SE, const int* fidx,
    const float* posw, const float* org, float* ws){
  int* iw=(int*)ws;
  int nf=iw[S_NF];
  int r0=blockIdx.x*64;
  if (r0>=nf) return;
  int c0=blockIdx.y*64;
  __shared__ float As[64][129];
  __shared__ float Wsh[64][129];
  __shared__ float pwl[384];
  __shared__ float px[64],py[64],pz[64];
  int t=threadIdx.x;
  bool needpos=(mode_in==1)||(mode_out==1);
  if (needpos){
    for (int i=t;i<384;i+=256) pwl[i]=posw[i];
    if (t<64){
      int r=r0+t;
      int q=(r<nf)? fidx[r]:0;
      int vx=q>>11, vy=(q>>4)&127, vz=q&15;
      px[t]=(vx+0.5f)*0.2f+org[0];
      py[t]=(vy+0.5f)*0.2f+org[1];
      pz[t]=(vz+0.5f)*0.2f+org[2];
    }
  }
  __syncthreads();
  for (int idx=t; idx<64*128; idx+=256){
    int rl=idx>>7, k=idx&127;
    int r=r0+rl;
    float v=0.f;
    if (r<nf){
      if (mode_in==1) v=SE[r*128+k]+px[rl]*pwl[k*3]+py[rl]*pwl[k*3+1]+pz[rl]*pwl[k*3+2];
      else v=A[r*128+k];
    }
    As[rl][k]=v;
    Wsh[rl][k]=W[(c0+rl)*128+k];
  }
  __syncthreads();
  int tx=t&15, ty=t>>4;
  float acc[4][4];
  #pragma unroll
  for (int i=0;i<4;i++)
    #pragma unroll
    for (int j=0;j<4;j++) acc[i][j]=0.f;
  #pragma unroll 8
  for (int k=0;k<128;k++){
    float a0=As[ty*4+0][k], a1=As[ty*4+1][k], a2=As[ty*4+2][k], a3=As[ty*4+3][k];
    float w0=Wsh[tx*4+0][k], w1=Wsh[tx*4+1][k], w2=Wsh[tx*4+2][k], w3=Wsh[tx*4+3][k];
    acc[0][0]+=a0*w0; acc[0][1]+=a0*w1; acc[0][2]+=a0*w2; acc[0][3]+=a0*w3;
    acc[1][0]+=a1*w0; acc[1][1]+=a1*w1; acc[1][2]+=a1*w2; acc[1][3]+=a1*w3;
    acc[2][0]+=a2*w0; acc[2][1]+=a2*w1; acc[2][2]+=a2*w2; acc[2][3]+=a2*w3;
    acc[3][0]+=a3*w0; acc[3][1]+=a3*w1; acc[3][2]+=a3*w2; acc[3][3]+=a3*w3;
  }
  for (int i=0;i<4;i++){
    int r=r0+ty*4+i;
    if (r>=nf) continue;
    for (int j=0;j<4;j++){
      int c=c0+tx*4+j;
      float v=acc[i][j]+bias[c];
      if (mode_out==1) v+=SE[r*128+c]+px[ty*4+i]*pwl[c*3]+py[ty*4+i]*pwl[c*3+1]+pz[ty*4+i]*pwl[c*3+2];
      C[r*128+c]=v;
    }
  }
}

__global__ __launch_bounds__(256) void kB2(const float* A1, float* A2, float* ws){
  int* iw=(int*)ws; float* fw=ws;
  int nf=iw[S_NF]; int n=iw[S_NINST];
  int r0=blockIdx.x*64;
  if (r0>=nf) return;
  __shared__ float kh[INST_MAX*128];
  __shared__ float vh[INST_MAX*128];
  __shared__ float ot[64][129];
  int t=threadIdx.x;
  for (int idx=t; idx<INST_MAX*128; idx+=256){
    kh[idx]=(idx<n*128)? fw[S_KHB+idx]:0.f;
    vh[idx]=(idx<n*128)? fw[S_VHB+idx]:0.f;
  }
  __syncthreads();
  int tokl=t&63, h=t>>6;
  int r=r0+tokl;
  bool valid=r<nf;
  float q[32];
  #pragma unroll
  for (int d=0;d<32;d++) q[d]=valid? A1[r*128+h*32+d]:0.f;
  float s[INST_MAX]; float mx=-1e30f;
  for (int j=0;j<INST_MAX;j++){
    float a=0.f;
    #pragma unroll
    for (int d=0;d<32;d++) a+=q[d]*kh[j*128+h*32+d];
    a*=RS32;
    s[j]=(j<n)? a:-1e30f;
    mx=fmaxf(mx,s[j]);
  }
  float sum=0.f;
  for (int j=0;j<INST_MAX;j++){ float p=expf(s[j]-mx); s[j]=p; sum+=p; }
  float inv=(n>0)? 1.0f/sum:0.f;
  float o[32];
  #pragma unroll
  for (int d=0;d<32;d++) o[d]=0.f;
  for (int j=0;j<INST_MAX;j++){
    float a=s[j]*inv;
    #pragma unroll
    for (int d=0;d<32;d++) o[d]+=a*vh[j*128+h*32+d];
  }
  #pragma unroll
  for (int d=0;d<32;d++) ot[tokl][h*32+d]=o[d];
  __syncthreads();
  for (int idx=t; idx<64*128; idx+=256){
    int rl=idx>>7, e=idx&127;
    if (r0+rl<nf) A2[(r0+rl)*128+e]=ot[rl][e];
  }
}

__global__ __launch_bounds__(256) void kLN(const float* A, float* B, const float* g, const float* b, float* ws){
  int* iw=(int*)ws;
  int nf=iw[S_NF];
  int t=threadIdx.x; int w=t>>6; int lane=t&63;
  int r=blockIdx.x*4+w;
  if (r>=nf) return;
  float v0=A[r*128+lane], v1=A[r*128+64+lane];
  float s=v0+v1;
  for (int o=32;o>0;o>>=1) s+=__shfl_xor(s,o);
  float mu=s*(1.0f/128.0f);
  float d0=v0-mu, d1=v1-mu;
  float vv=d0*d0+d1*d1;
  for (int o=32;o>0;o>>=1) vv+=__shfl_xor(vv,o);
  float rsv=rsqrtf(vv*(1.0f/128.0f)+1e-5f);
  B[r*128+lane]=d0*rsv*g[lane]+b[lane];
  B[r*128+64+lane]=d1*rsv*g[64+lane]+b[64+lane];
}

__global__ void k_transpose(const float* in, float* outp, int R, int C){
  __shared__ float tile[32][33];
  int bx=blockIdx.x*32, by=blockIdx.y*32;
  int tx=threadIdx.x, ty=threadIdx.y;
  for (int k=0;k<4;k++){
    int r=by+ty+k*8, c=bx+tx;
    if (r<R && c<C) tile[ty+k*8][tx]=in[(size_t)r*C+c];
  }
  __syncthreads();
  for (int k=0;k<4;k++){
    int cc=bx+ty+k*8, rr=by+tx;
    if (rr<R && cc<C) outp[(size_t)cc*R+rr]=tile[tx][ty+k*8];
  }
}

__global__ __launch_bounds__(256) void kFFN(const float* X_, float* SEo, const float* W1T, const float* W2T,
    const float* b1, const float* b2, const float* g, const float* bb, float* ws){
  int* iw=(int*)ws;
  int nf=iw[S_NF];
  int r0=blockIdx.x*16;
  if (r0>=nf) return;
  __shared__ float X[16][129];
  __shared__ float Hl[16][516];
  __shared__ float yl[16][129];
  int t=threadIdx.x;
  for (int idx=t; idx<16*128; idx+=256){
    int rl=idx>>7, e=idx&127;
    int r=r0+rl;
    X[rl][e]=(r<nf)? X_[r*128+e]:0.f;
  }
  __syncthreads();
  #pragma unroll
  for (int pass=0; pass<2; pass++){
    int d=t+pass*256;
    float acc[16];
    #pragma unroll
    for (int rl=0;rl<16;rl++) acc[rl]=0.f;
    for (int k=0;k<128;k++){
      float w=W1T[k*512+d];
      #pragma unroll
      for (int rl=0;rl<16;rl++) acc[rl]+=w*X[rl][k];
    }
    float bd=b1[d];
    #pragma unroll
    for (int rl=0;rl<16;rl++) Hl[rl][d]=fmaxf(acc[rl]+bd,0.f);
  }
  __syncthreads();
  {
    int e=t&127, g2=t>>7;
    float a2[8];
    #pragma unroll
    for (int rr=0;rr<8;rr++) a2[rr]=0.f;
    for (int d=0;d<512;d++){
      float w=W2T[d*128+e];
      #pragma unroll
      for (int rr=0;rr<8;rr++) a2[rr]+=w*Hl[g2*8+rr][d];
    }
    float be=b2[e];
    #pragma unroll
    for (int rr=0;rr<8;rr++){ int rl=g2*8+rr; yl[rl][e]=a2[rr]+be+X[rl][e]; }
  }
  __syncthreads();
  int w=t>>6, lane=t&63;
  for (int rl=w; rl<16; rl+=4){
    int r=r0+rl;
    float v0=yl[rl][lane], v1=yl[rl][64+lane];
    float s=v0+v1;
    for (int o=32;o>0;o>>=1) s+=__shfl_xor(s,o);
    float mu=s*(1.f/128.f);
    float d0=v0-mu, d1=v1-mu;
    float vv=d0*d0+d1*d1;
    for (int o=32;o>0;o>>=1) vv+=__shfl_xor(vv,o);
    float rsv=rsqrtf(vv*(1.f/128.f)+1e-5f);
    if (r<nf){
      SEo[r*128+lane]=d0*rsv*g[lane]+bb[lane];
      SEo[r*128+64+lane]=d1*rsv*g[64+lane]+bb[64+lane];
    }
  }
}

__global__ __launch_bounds__(256) void k_out(const float* SE, const float* sew, const float* x3d,
    const float* convw, const float* convb, const int* invr, float* out, float* ws){
  (void)ws;
  __shared__ float rows[64][129];
  __shared__ float cw[20*128];
  __shared__ float cb[20];
  __shared__ int rkl[64];
  int t=threadIdx.x;
  int q0=blockIdx.x*64;
  for (int idx=t; idx<20*128; idx+=256) cw[idx]=convw[idx];
  if (t<20) cb[t]=convb[t];
  if (t<64) rkl[t]=invr[q0+t];
  __syncthreads();
  for (int idx=t; idx<64*128; idx+=256){
    int v=idx>>7, e=idx&127;
    int rk=rkl[v];
    rows[v][e]=(rk>=0)? SE[rk*128+e]:sew[(size_t)(q0+v)*128+e];
  }
  __syncthreads();
  for (int idx=t; idx<128*64; idx+=256){
    int c=idx>>6, v=idx&63;
    if (rkl[v]<0) rows[v][c]+=x3d[(size_t)c*NQ+q0+v];
  }
  __syncthreads();
  int v=t&63;
  for (int o=t>>6; o<20; o+=4){
    float a=cb[o];
    const float* cr=cw+o*128;
    for (int c=0;c<128;c++) a+=rows[v][c]*cr[c];
    out[(size_t)o*NQ+q0+v]=a;
  }
}

extern "C" void kernel_launch(void* const* d_in, const int* in_sizes, int n_in,
                              void* d_out, int out_size, void* d_ws, size_t ws_size,
                              hipStream_t stream){
  (void)in_sizes; (void)n_in; (void)out_size; (void)ws_size;
  const float* queries  = (const float*)d_in[0];
  const float* plogits  = (const float*)d_in[1];
  const float* pmasks   = (const float*)d_in[2];
  const float* x3d      = (const float*)d_in[3];
  const float* depth    = (const float*)d_in[4];
  const float* Kmat     = (const float*)d_in[5];
  const float* Emat     = (const float*)d_in[6];
  const float* vorigin  = (const float*)d_in[7];
  const int*   fov      = (const int*)d_in[8];
  const float* sew      = (const float*)d_in[9];
  const float* instposw = (const float*)d_in[10];
  const float* posw     = (const float*)d_in[11];
  const float* convw    = (const float*)d_in[12];
  const float* convb    = (const float*)d_in[13];
  const float* AW       = (const float*)d_in[14];
  const float* AB       = (const float*)d_in[15];
  const float* LG       = (const float*)d_in[16];
  const float* LB       = (const float*)d_in[17];
  const float* F1W      = (const float*)d_in[18];
  const float* F1B      = (const float*)d_in[19];
  const float* F2W      = (const float*)d_in[20];
  const float* F2B      = (const float*)d_in[21];
  float* out = (float*)d_out;
  char* wsb = (char*)d_ws;
  float* fws = (float*)d_ws;
  int* fidx = (int*)(wsb + OFF_FIDX);
  int* invr = (int*)(wsb + OFF_INV);
  float* W1T = (float*)(wsb + OFF_W1T);
  float* W2T = (float*)(wsb + OFF_W2T);
  float* SE = (float*)(wsb + OFF_SE);
  float* A1 = (float*)(wsb + OFF_A1);
  float* A2 = (float*)(wsb + OFF_A2);
  float* SC = (float*)(wsb + OFF_SC);

  auto aw  = [&](int i,int br,int m){ return AW + (size_t)(((i*2+br)*4+m))*128*128; };
  auto ab  = [&](int i,int br,int m){ return AB + (size_t)(((i*2+br)*4+m))*128; };
  auto lng = [&](int i,int br,int wch){ return LG + (size_t)(((i*2+br)*2+wch))*128; };
  auto lnb = [&](int i,int br,int wch){ return LB + (size_t)(((i*2+br)*2+wch))*128; };
  auto f1w = [&](int i,int br){ return F1W + (size_t)(i*2+br)*512*128; };
  auto f1b = [&](int i,int br){ return F1B + (size_t)(i*2+br)*512; };
  auto f2w = [&](int i,int br){ return F2W + (size_t)(i*2+br)*128*512; };
  auto f2b = [&](int i,int br){ return F2B + (size_t)(i*2+br)*128; };

  const int NB64 = NF_MAX/64;   // 1152
  const int NB16 = NF_MAX/16;   // 4608
  const int NB4  = NF_MAX/4;    // 18432

  k_init<<<1,256,0,stream>>>(Kmat,Emat,fws);
  k_score<<<1,320,0,stream>>>(plogits,fws);
  k_winner<<<NPIX/256,256,0,stream>>>(pmasks,depth,fws);
  k_sel<<<1,256,0,stream>>>(queries,instposw,posw,fws);
  k_fov_count<<<256,256,0,stream>>>(fov,fws);
  k_fov_scan<<<1,64,0,stream>>>(fws);
  k_fov_scatter<<<256,256,0,stream>>>(fov,fws);
  k_se_build<<<NB64,256,0,stream>>>(sew,x3d,fidx,SE,fws);

  for (int i=0;i<2;i++){
    // ---- instance-side layer (queries = instances, keys/vals = scene) ----
    kA_prep<<<1,256,0,stream>>>(aw(i,0,0),ab(i,0,0),aw(i,0,1),ab(i,0,1),fws);
    kS1<<<NB64,256,0,stream>>>(SE,SC,posw,vorigin,fidx,fws);
    kS2S3<<<IH_MAX,256,0,stream>>>(SC,fws);
    kS4<<<256,256,0,stream>>>(SC,SE,fws);
    kA_post<<<1,256,0,stream>>>(aw(i,0,2),ab(i,0,2),aw(i,0,3),ab(i,0,3),lng(i,0,0),lnb(i,0,0),fws);
    kA_ffn<<<INST_MAX,256,0,stream>>>(f1w(i,0),f1b(i,0),f2w(i,0),f2b(i,0),lng(i,0,1),lnb(i,0,1),fws);
    kA_kv<<<1,256,0,stream>>>(aw(i,1,1),ab(i,1,1),aw(i,1,2),ab(i,1,2),fws);
    // ---- scene-side layer (queries = scene, keys/vals = instances) ----
    kGEMM<<<dim3(NB64,2),256,0,stream>>>(nullptr,A1,aw(i,1,0),ab(i,1,0),1,0,SE,fidx,posw,vorigin,fws);
    kB2<<<NB64,256,0,stream>>>(A1,A2,fws);
    kGEMM<<<dim3(NB64,2),256,0,stream>>>(A2,A1,aw(i,1,3),ab(i,1,3),0,1,SE,fidx,posw,vorigin,fws);
    kLN<<<NB4,256,0,stream>>>(A1,A2,lng(i,1,0),lnb(i,1,0),fws);
    k_transpose<<<dim3(4,16),dim3(32,8),0,stream>>>(f1w(i,1),W1T,512,128);
    k_transpose<<<dim3(16,4),dim3(32,8),0,stream>>>(f2w(i,1),W2T,128,512);
    kFFN<<<NB16,256,0,stream>>>(A2,SE,W1T,W2T,f1b(i,1),f2b(i,1),lng(i,1,1),lnb(i,1,1),fws);
  }
  k_out<<<NQ/64,256,0,stream>>>(SE,sew,x3d,convw,convb,invr,out,fws);
}

// Round 2
// 2781.790 us; speedup vs baseline: 1.2961x; 1.2961x over previous
//
#include <hip/hip_runtime.h>
#include <math.h>

#define EMBED 128
#define NCLS 21
#define NI_ 300
#define IMH 96
#define IMW 320
#define NPIX (IMH*IMW)
#define NQ 262144
#define NF_MAX 73728
#define INST_MAX 16
#define IH_MAX 64
#define RS32 0.17677669529663687f

// ---- SMALL region layout (4-byte units at ws base) ----
#define S_NF 0
#define S_NK 1
#define S_NINST 2
#define S_NIH 3
#define S_INVK 8      // 9 f
#define S_INVE 24     // 16 f
#define S_KIDX 64     // 300 i
#define S_SKK 400     // 300 f
#define S_MAREA 768   // 300 i
#define S_PAREA 1088  // 300 i
#define S_AREA2 1408  // 300 i
#define S_XYZ 1728    // 900 f
#define S_SELJ 2656   // 16 i
#define S_K2 2688     // 16 i
#define S_FCNT 3072   // 256 i
#define S_FOFF 3328   // 256 i
#define S_INSTQ 4096  // 16*128 f
#define S_INSTP 6144
#define S_QIN 8192
#define S_QH 10240
#define S_XI 12288
#define S_KHB 16384
#define S_VHB 18432
#define S_QKT 20480   // 64*128 f
#define S_SB 28672    // 64 f
#define S_SUMV 28928  // 64 f
#define S_WSUM 29056  // 64*128 f

#define OFF_FIDX ((size_t)1<<20)
#define OFF_INV  ((size_t)2<<20)
#define OFF_W1T  ((size_t)3<<20)
#define OFF_W2T  (((size_t)3<<20) + 512*128*4)
#define OFF_SE   ((size_t)4<<20)
#define SE_BYTES ((size_t)NF_MAX*128*4)
#define OFF_A1   (OFF_SE + SE_BYTES)
#define OFF_A2   (OFF_A1 + SE_BYTES)
#define OFF_SC   (OFF_A2 + SE_BYTES)

__global__ __launch_bounds__(256) void k_init(const float* Km, const float* Em, float* ws){
  int* iw = (int*)ws;
  for (int i = threadIdx.x; i < 4096; i += 256) iw[i] = 0;
  __syncthreads();
  if (threadIdx.x == 0){
    float* fw = ws;
    const float* K = Km;
    float A = K[4]*K[8]-K[5]*K[7];
    float B = K[5]*K[6]-K[3]*K[8];
    float C = K[3]*K[7]-K[4]*K[6];
    float det = K[0]*A + K[1]*B + K[2]*C;
    float id = 1.0f/det;
    fw[S_INVK+0] = A*id;
    fw[S_INVK+1] = (K[2]*K[7]-K[1]*K[8])*id;
    fw[S_INVK+2] = (K[1]*K[5]-K[2]*K[4])*id;
    fw[S_INVK+3] = B*id;
    fw[S_INVK+4] = (K[0]*K[8]-K[2]*K[6])*id;
    fw[S_INVK+5] = (K[2]*K[3]-K[0]*K[5])*id;
    fw[S_INVK+6] = C*id;
    fw[S_INVK+7] = (K[1]*K[6]-K[0]*K[7])*id;
    fw[S_INVK+8] = (K[0]*K[4]-K[1]*K[3])*id;
    // 4x4 Gauss-Jordan inverse of E
    float M[4][8];
    for (int r=0;r<4;r++){ for(int c=0;c<4;c++){ M[r][c]=Em[r*4+c]; M[r][4+c]=(r==c)?1.f:0.f; } }
    for (int col=0; col<4; col++){
      int piv=col; float best=fabsf(M[col][col]);
      for (int r=col+1;r<4;r++){ float v=fabsf(M[r][col]); if(v>best){best=v;piv=r;} }
      if (piv!=col){ for(int c=0;c<8;c++){ float tmp=M[col][c]; M[col][c]=M[piv][c]; M[piv][c]=tmp; } }
      float inv=1.0f/M[col][col];
      for (int c=0;c<8;c++) M[col][c]*=inv;
      for (int r=0;r<4;r++){ if(r==col) continue; float f=M[r][col]; for(int c=0;c<8;c++) M[r][c]-=f*M[col][c]; }
    }
    for (int r=0;r<4;r++) for(int c=0;c<4;c++) fw[S_INVE+r*4+c]=M[r][4+c];
  }
}

__global__ __launch_bounds__(320) void k_score(const float* logits, float* ws){
  int* iw=(int*)ws; float* fw=ws;
  __shared__ float ssc[NI_];
  __shared__ int skp[NI_];
  int t=threadIdx.x;
  if (t < NI_){
    float v[NCLS]; float mx=-1e30f;
    for (int c=0;c<NCLS;c++){
      float l=logits[t*NCLS+c];
      float sg=1.0f/(1.0f+expf(-l));
      float x=sg/0.06f;
      v[c]=x; mx=fmaxf(mx,x);
    }
    float s=0.f;
    for (int c=0;c<NCLS;c++) s += expf(v[c]-mx);
    float score=1.0f/s;     // max softmax prob
    ssc[t]=score; skp[t]=(score>0.25f)?1:0;
  }
  __syncthreads();
  if (t==0){
    int nk=0;
    for (int i=0;i<NI_;i++){ if(skp[i]){ iw[S_KIDX+nk]=i; fw[S_SKK+nk]=ssc[i]; nk++; } }
    iw[S_NK]=nk;
  }
}

// Block-level pre-reduction: per-query partial counts/sums in LDS, then
// at most nk*6 global atomics per block (was ~6 per PIXEL -> 180k fully
// contended device atomics = the 770us stall).
__global__ __launch_bounds__(256) void k_winner(const float* pmask, const float* depth, float* ws){
  int* iw=(int*)ws; float* fw=ws;
  int nk=iw[S_NK];
  if (nk>NI_) nk=NI_;
  __shared__ int s_pa[NI_], s_ma[NI_], s_a2[NI_];
  __shared__ float s_x[NI_], s_y[NI_], s_z[NI_];
  __shared__ int s_gi[NI_];
  __shared__ float s_sc[NI_];
  int t=threadIdx.x;
  int lane=t&63;
  for (int j=t;j<nk;j+=256){
    s_pa[j]=0; s_ma[j]=0; s_a2[j]=0;
    s_x[j]=0.f; s_y[j]=0.f; s_z[j]=0.f;
    s_gi[j]=iw[S_KIDX+j]; s_sc[j]=fw[S_SKK+j];
  }
  __syncthreads();
  int p=blockIdx.x*256+t;
  float best=-1e30f; int jw=-1; float mw=0.f;
  for (int j=0;j<nk;j++){
    float m=1.0f/(1.0f+expf(-pmask[(size_t)s_gi[j]*NPIX+p]));
    unsigned long long msk=__ballot(m>=0.5f);
    if (lane==0 && msk) atomicAdd(&s_pa[j], __popcll(msk));
    float wv=s_sc[j]*m;
    if (wv>best){ best=wv; jw=j; mw=m; }
  }
  if (jw>=0){
    atomicAdd(&s_ma[jw],1);
    if (mw>=0.5f){
      atomicAdd(&s_a2[jw],1);
      float d=depth[p];
      float gx=(float)(p%IMW)*4.0f, gy=(float)(p/IMW)*4.0f;
      float X=gx*d, Y=gy*d;
      const float* iK=fw+S_INVK; const float* iE=fw+S_INVE;
      float c0=iK[0]*X+iK[1]*Y+iK[2]*d;
      float c1=iK[3]*X+iK[4]*Y+iK[5]*d;
      float c2=iK[6]*X+iK[7]*Y+iK[8]*d;
      float wx=iE[0]*c0+iE[1]*c1+iE[2]*c2+iE[3];
      float wy=iE[4]*c0+iE[5]*c1+iE[6]*c2+iE[7];
      float wz=iE[8]*c0+iE[9]*c1+iE[10]*c2+iE[11];
      atomicAdd(&s_x[jw],wx);
      atomicAdd(&s_y[jw],wy);
      atomicAdd(&s_z[jw],wz);
    }
  }
  __syncthreads();
  for (int j=t;j<nk;j+=256){
    if (s_pa[j]) atomicAdd(&iw[S_PAREA+j],s_pa[j]);
    if (s_ma[j]) atomicAdd(&iw[S_MAREA+j],s_ma[j]);
    if (s_a2[j]) atomicAdd(&iw[S_AREA2+j],s_a2[j]);
    if (s_x[j]!=0.f) atomicAdd(&fw[S_XYZ+j*3+0],s_x[j]);
    if (s_y[j]!=0.f) atomicAdd(&fw[S_XYZ+j*3+1],s_y[j]);
    if (s_z[j]!=0.f) atomicAdd(&fw[S_XYZ+j*3+2],s_z[j]);
  }
}

__global__ __launch_bounds__(256) void k_sel(const float* queries, const float* instposw, const float* posw, float* ws){
  int* iw=(int*)ws; float* fw=ws;
  __shared__ int sn;
  if (threadIdx.x==0){
    int nk=iw[S_NK]; int n=0;
    for (int j=0;j<nk;j++){
      int a2=iw[S_AREA2+j];
      if (a2>0){
        float r=(float)iw[S_MAREA+j]/(float)iw[S_PAREA+j];
        if (r>=0.8f && n<INST_MAX){ iw[S_SELJ+n]=j; iw[S_K2+n]=iw[S_KIDX+j]; n++; }
      }
    }
    iw[S_NINST]=n; iw[S_NIH]=4*n; sn=n;
  }
  __syncthreads();
  int n=sn;
  for (int idx=threadIdx.x; idx<n*128; idx+=256){
    int i=idx>>7, e=idx&127;
    int j=iw[S_SELJ+i]; int gi=iw[S_K2+i];
    fw[S_INSTQ+idx]=queries[gi*128+e];
    float mp=fw[S_XYZ+j*3]*posw[e*3]+fw[S_XYZ+j*3+1]*posw[e*3+1]+fw[S_XYZ+j*3+2]*posw[e*3+2];
    fw[S_INSTP+idx]=instposw[gi*128+e]+mp;
  }
}

__global__ __launch_bounds__(256) void k_fov_count(const int* fov, float* ws){
  int* iw=(int*)ws;
  __shared__ int red[256];
  int t=threadIdx.x;
  int base=blockIdx.x*1024;
  int s=0;
  for (int k=0;k<4;k++) s += (fov[base+k*256+t]!=0)?1:0;
  red[t]=s; __syncthreads();
  for (int st=128;st>0;st>>=1){ if(t<st) red[t]+=red[t+st]; __syncthreads(); }
  if (t==0) iw[S_FCNT+blockIdx.x]=red[0];
}

__global__ void k_fov_scan(float* ws){
  int* iw=(int*)ws;
  if (threadIdx.x==0){
    int acc=0;
    for (int b=0;b<256;b++){ iw[S_FOFF+b]=acc; acc+=iw[S_FCNT+b]; }
    iw[S_NF]=(acc<NF_MAX)?acc:NF_MAX;
  }
}

__global__ __launch_bounds__(256) void k_fov_scatter(const int* fov, float* ws){
  int* iw=(int*)ws;
  int* fidx=(int*)((char*)ws+OFF_FIDX);
  int* invr=(int*)((char*)ws+OFF_INV);
  __shared__ int wsums[4];
  __shared__ int woff[4];
  __shared__ int cur;
  __shared__ int tot;
  int t=threadIdx.x; int w=t>>6; int lane=t&63;
  if (t==0) cur=iw[S_FOFF+blockIdx.x];
  __syncthreads();
  int base=blockIdx.x*1024;
  for (int k=0;k<4;k++){
    int i=base+k*256+t;
    int f=(fov[i]!=0)?1:0;
    unsigned long long m=__ballot(f);
    int rk=__popcll(m & ((lane==0)?0ull:((~0ull)>>(64-lane))));
    if (lane==0) wsums[w]=__popcll(m);
    __syncthreads();
    if (t==0){ int a=0; for(int q2=0;q2<4;q2++){ woff[q2]=a; a+=wsums[q2]; } tot=a; }
    __syncthreads();
    if (f){
      int r=cur+woff[w]+rk;
      if (r<NF_MAX){ fidx[r]=i; invr[i]=r; } else invr[i]=-1;
    } else invr[i]=-1;
    __syncthreads();
    if (t==0) cur+=tot;
    __syncthreads();
  }
}

__global__ __launch_bounds__(256) void k_se_build(const float* sew, const float* x3d, const int* fidx, float* SE, float* ws){
  int* iw=(int*)ws;
  int nf=iw[S_NF];
  int r0=blockIdx.x*64;
  if (r0>=nf) return;
  int nr=min(64,nf-r0);
  __shared__ float tile[64][129];
  __shared__ int fidxl[64];
  int t=threadIdx.x;
  if (t<64) fidxl[t]=(t<nr)? fidx[r0+t]:0;
  __syncthreads();
  for (int idx=t; idx<64*128; idx+=256){
    int v=idx>>7, e=idx&127;
    tile[v][e]=(v<nr)? sew[(size_t)fidxl[v]*128+e]:0.f;
  }
  __syncthreads();
  for (int idx=t; idx<128*64; idx+=256){
    int c=idx>>6, v=idx&63;
    if (v<nr) tile[v][c]+=x3d[(size_t)c*NQ+fidxl[v]];
  }
  __syncthreads();
  for (int idx=t; idx<64*128; idx+=256){
    int v=idx>>7, e=idx&127;
    if (v<nr) SE[(r0+v)*128+e]=tile[v][e];
  }
}

__global__ __launch_bounds__(256) void kA_prep(const float* Wq, const float* bq, const float* Wk, const float* bk, float* ws){
  int* iw=(int*)ws; float* fw=ws;
  int n=iw[S_NINST]; int nih=iw[S_NIH];
  int t=threadIdx.x;
  for (int idx=t; idx<n*128; idx+=256) fw[S_QIN+idx]=fw[S_INSTQ+idx]+fw[S_INSTP+idx];
  __syncthreads();
  for (int idx=t; idx<n*128; idx+=256){
    int i=idx>>7, e=idx&127;
    float a=bq[e];
    for (int k=0;k<128;k++) a+=fw[S_QIN+i*128+k]*Wq[e*128+k];
    fw[S_QH+idx]=a;
  }
  __syncthreads();
  for (int idx=t; idx<nih*128; idx+=256){
    int ih=idx>>7, e=idx&127;
    int i=ih>>2, h=ih&3;
    float a=0.f;
    for (int d=0;d<32;d++) a+=fw[S_QH+i*128+h*32+d]*Wk[(h*32+d)*128+e];
    fw[S_QKT+idx]=a*RS32;
  }
  for (int ih=t; ih<nih; ih+=256){
    int i=ih>>2, h=ih&3;
    float a=0.f;
    for (int d=0;d<32;d++) a+=fw[S_QH+i*128+h*32+d]*bk[h*32+d];
    fw[S_SB+ih]=a*RS32;
  }
}

__global__ __launch_bounds__(256) void kS1(const float* SE, float* SC, const float* posw, const float* org, const int* fidx, float* ws){
  int* iw=(int*)ws; float* fw=ws;
  int nf=iw[S_NF]; int nih=iw[S_NIH];
  int r0=blockIdx.x*64;
  if (r0>=nf || nih==0) return;
  int nr=min(64,nf-r0);
  __shared__ float xt[64][129];
  __shared__ float qk[IH_MAX*128];
  __shared__ float sbl[IH_MAX];
  __shared__ float pwl[384];
  __shared__ float px[64],py[64],pz[64];
  __shared__ int fidxl[64];
  int t=threadIdx.x;
  for (int i=t;i<384;i+=256) pwl[i]=posw[i];
  if (t<64) fidxl[t]=(t<nr)? fidx[r0+t]:0;
  for (int idx=t; idx<nih*128; idx+=256) qk[idx]=fw[S_QKT+idx];
  if (t<IH_MAX) sbl[t]=(t<nih)? fw[S_SB+t]:0.f;
  __syncthreads();
  if (t<64){
    int q=fidxl[t];
    int vx=q>>11, vy=(q>>4)&127, vz=q&15;
    px[t]=(vx+0.5f)*0.2f+org[0];
    py[t]=(vy+0.5f)*0.2f+org[1];
    pz[t]=(vz+0.5f)*0.2f+org[2];
  }
  __syncthreads();
  for (int idx=t; idx<64*128; idx+=256){
    int v=idx>>7, e=idx&127;
    float val=0.f;
    if (v<nr) val=SE[(r0+v)*128+e]+px[v]*pwl[e*3]+py[v]*pwl[e*3+1]+pz[v]*pwl[e*3+2];
    xt[v][e]=val;
  }
  __syncthreads();
  int tokl=t&63, base=t>>6;
  for (int ih=base; ih<nih; ih+=4){
    float a=sbl[ih];
    const float* qrow=qk+ih*128;
    for (int e=0;e<128;e++) a+=qrow[e]*xt[tokl][e];
    if (tokl<nr) SC[(size_t)ih*NF_MAX+r0+tokl]=a;
  }
}

__global__ __launch_bounds__(256) void kS2S3(float* SC, float* ws){
  int* iw=(int*)ws; float* fw=ws;
  int nih=iw[S_NIH]; int ih=blockIdx.x;
  if (ih>=nih) return;
  int nf=iw[S_NF];
  float* row=SC+(size_t)ih*NF_MAX;
  __shared__ float red[256];
  int t=threadIdx.x;
  float m=-1e30f;
  for (int j=t;j<nf;j+=256) m=fmaxf(m,row[j]);
  red[t]=m; __syncthreads();
  for (int s=128;s>0;s>>=1){ if(t<s) red[t]=fmaxf(red[t],red[t+s]); __syncthreads(); }
  m=red[0]; __syncthreads();
  float sum=0.f;
  for (int j=t;j<nf;j+=256){ float p=expf(row[j]-m); row[j]=p; sum+=p; }
  red[t]=sum; __syncthreads();
  for (int s=128;s>0;s>>=1){ if(t<s) red[t]+=red[t+s]; __syncthreads(); }
  if (t==0) fw[S_SUMV+ih]=red[0];
  if (t<128) fw[S_WSUM+ih*128+t]=0.f;
}

__global__ __launch_bounds__(256) void kS4(const float* SC, const float* SE, float* ws){
  int* iw=(int*)ws; float* fw=ws;
  int nf=iw[S_NF]; int nih=iw[S_NIH];
  if (nih==0) return;
  int t=threadIdx.x;
  int chunk=(nf+255)/256;
  int j0=blockIdx.x*chunk;
  int j1=min(nf,j0+chunk);
  if (j0>=j1) return;
  __shared__ float pt[64*64];
  int e=t&127, half=t>>7;
  float acc[32];
  #pragma unroll
  for (int r=0;r<32;r++) acc[r]=0.f;
  for (int jj=j0; jj<j1; jj+=64){
    int cnt=min(64,j1-jj);
    __syncthreads();
    for (int idx=t; idx<64*64; idx+=256){
      int ih=idx>>6, jl=idx&63;
      pt[idx]=(ih<nih && jl<cnt)? SC[(size_t)ih*NF_MAX+jj+jl]:0.f;
    }
    __syncthreads();
    for (int jl=0; jl<cnt; jl++){
      float sv=SE[(jj+jl)*128+e];
      #pragma unroll
      for (int r=0;r<32;r++) acc[r]+=pt[(half*32+r)*64+jl]*sv;
    }
  }
  #pragma unroll
  for (int r=0;r<32;r++) atomicAdd(&fw[S_WSUM+(half*32+r)*128+e], acc[r]);
}

__global__ __launch_bounds__(256) void kA_post(const float* Wv, const float* bv, const float* Wo, const float* bo,
    const float* g, const float* bb, float* ws){
  int* iw=(int*)ws; float* fw=ws;
  int n=iw[S_NINST]; int nih=iw[S_NIH];
  __shared__ float wn[IH_MAX*128];
  __shared__ float ol[INST_MAX*128];
  __shared__ float tl[INST_MAX*128];
  int t=threadIdx.x;
  for (int idx=t; idx<nih*128; idx+=256){
    int ih=idx>>7;
    wn[idx]=fw[S_WSUM+idx]/fw[S_SUMV+ih];
  }
  __syncthreads();
  for (int idx=t; idx<n*128; idx+=256){
    int i=idx>>7, f=idx&127; int h=f>>5;
    float a=bv[f];
    const float* wrow=Wv+f*128;
    const float* wv=wn+(i*4+h)*128;
    for (int e2=0;e2<128;e2++) a+=wrow[e2]*wv[e2];
    ol[idx]=a;
  }
  __syncthreads();
  for (int idx=t; idx<n*128; idx+=256){
    int i=idx>>7, e2=idx&127;
    float a=bo[e2];
    const float* orow=ol+i*128;
    const float* wrow=Wo+e2*128;
    for (int f2=0;f2<128;f2++) a+=orow[f2]*wrow[f2];
    tl[idx]=a+fw[S_QIN+idx];
  }
  __syncthreads();
  int w=t>>6, lane=t&63;
  for (int i=w;i<n;i+=4){
    float v0=tl[i*128+lane], v1=tl[i*128+64+lane];
    float s=v0+v1;
    for (int o=32;o>0;o>>=1) s+=__shfl_xor(s,o);
    float mu=s*(1.f/128.f);
    float d0=v0-mu, d1=v1-mu;
    float vv=d0*d0+d1*d1;
    for (int o=32;o>0;o>>=1) vv+=__shfl_xor(vv,o);
    float rsv=rsqrtf(vv*(1.f/128.f)+1e-5f);
    fw[S_XI+i*128+lane]=d0*rsv*g[lane]+bb[lane];
    fw[S_XI+i*128+64+lane]=d1*rsv*g[64+lane]+bb[64+lane];
  }
}

__global__ __launch_bounds__(256) void kA_ffn(const float* W1, const float* b1, const float* W2, const float* b2,
    const float* g, const float* bb, float* ws){
  int* iw=(int*)ws; float* fw=ws;
  int n=iw[S_NINST];
  int i=blockIdx.x;
  if (i>=n) return;
  __shared__ float xl[128];
  __shared__ float hid[512];
  __shared__ float yv[128];
  int t=threadIdx.x;
  if (t<128) xl[t]=fw[S_XI+i*128+t];
  __syncthreads();
  for (int d=t; d<512; d+=256){
    float a=b1[d];
    const float* wr=W1+d*128;
    for (int k=0;k<128;k++) a+=wr[k]*xl[k];
    hid[d]=fmaxf(a,0.f);
  }
  __syncthreads();
  if (t<128){
    float a=b2[t];
    const float* wr=W2+(size_t)t*512;
    for (int d=0;d<512;d++) a+=wr[d]*hid[d];
    yv[t]=a+xl[t];
  }
  __syncthreads();
  if (t<64){
    float v0=yv[t], v1=yv[t+64];
    float s=v0+v1;
    for (int o=32;o>0;o>>=1) s+=__shfl_xor(s,o);
    float mu=s*(1.f/128.f);
    float d0=v0-mu, d1=v1-mu;
    float vv=d0*d0+d1*d1;
    for (int o=32;o>0;o>>=1) vv+=__shfl_xor(vv,o);
    float rsv=rsqrtf(vv*(1.f/128.f)+1e-5f);
    fw[S_INSTQ+i*128+t]=d0*rsv*g[t]+bb[t];
    fw[S_INSTQ+i*128+64+t]=d1*rsv*g[64+t]+bb[64+t];
  }
}

__global__ __launch_bounds__(256) void kA_kv(const float* Wk2, const float* bk2, const float* Wv2, const float* bv2, float* ws){
  int* iw=(int*)ws; float* fw=ws;
  int n=iw[S_NINST];
  int t=threadIdx.x;
  for (int idx=t; idx<n*128; idx+=256){
    int i=idx>>7, e=idx&127;
    float ak=bk2[e], av=bv2[e];
    const float* wk=Wk2+e*128;
    const float* wv=Wv2+e*128;
    for (int k=0;k<128;k++){
      float qv=fw[S_INSTQ+i*128+k];
      float qp=qv+fw[S_INSTP+i*128+k];
      ak+=qp*wk[k];
      av+=qv*wv[k];
    }
    fw[S_KHB+idx]=ak; fw[S_VHB+idx]=av;
  }
}

__global__ __launch_bounds__(256) void kGEMM(const float* A, float* C, const float* W, const float* bias,
    int mode_in, int mode_out, const float* SE, const int* fidx,
    const float* posw, const float* org, float* ws){
  int* iw=(int*)ws;
  int nf=iw[S_NF];
  int r0=blockIdx.x*64;
  if (r0>=nf) return;
  int c0=blockIdx.y*64;
  __shared__ float As[64][129];
  __shared__ float Wsh[64][129];
  __shared__ float pwl[384];
  __shared__ float px[64],py[64],pz[64];
  int t=threadIdx.x;
  bool needpos=(mode_in==1)||(mode_out==1);
  if (needpos){
    for (int i=t;i<384;i+=256) pwl[i]=posw[i];
    if (t<64){
      int r=r0+t;
      int q=(r<nf)? fidx[r]:0;
      int vx=q>>11, vy=(q>>4)&127, vz=q&15;
      px[t]=(vx+0.5f)*0.2f+org[0];
      py[t]=(vy+0.5f)*0.2f+org[1];
      pz[t]=(vz+0.5f)*0.2f+org[2];
    }
  }
  __syncthreads();
  for (int idx=t; idx<64*128; idx+=256){
    int rl=idx>>7, k=idx&127;
    int r=r0+rl;
    float v=0.f;
    if (r<nf){
      if (mode_in==1) v=SE[r*128+k]+px[rl]*pwl[k*3]+py[rl]*pwl[k*3+1]+pz[rl]*pwl[k*3+2];
      else v=A[r*128+k];
    }
    As[rl][k]=v;
    Wsh[rl][k]=W[(c0+rl)*128+k];
  }
  __syncthreads();
  int tx=t&15, ty=t>>4;
  float acc[4][4];
  #pragma unroll
  for (int i=0;i<4;i++)
    #pragma unroll
    for (int j=0;j<4;j++) acc[i][j]=0.f;
  #pragma unroll 8
  for (int k=0;k<128;k++){
    float a0=As[ty*4+0][k], a1=As[ty*4+1][k], a2=As[ty*4+2][k], a3=As[ty*4+3][k];
    float w0=Wsh[tx*4+0][k], w1=Wsh[tx*4+1][k], w2=Wsh[tx*4+2][k], w3=Wsh[tx*4+3][k];
    acc[0][0]+=a0*w0; acc[0][1]+=a0*w1; acc[0][2]+=a0*w2; acc[0][3]+=a0*w3;
    acc[1][0]+=a1*w0; acc[1][1]+=a1*w1; acc[1][2]+=a1*w2; acc[1][3]+=a1*w3;
    acc[2][0]+=a2*w0; acc[2][1]+=a2*w1; acc[2][2]+=a2*w2; acc[2][3]+=a2*w3;
    acc[3][0]+=a3*w0; acc[3][1]+=a3*w1; acc[3][2]+=a3*w2; acc[3][3]+=a3*w3;
  }
  for (int i=0;i<4;i++){
    int r=r0+ty*4+i;
    if (r>=nf) continue;
    for (int j=0;j<4;j++){
      int c=c0+tx*4+j;
      float v=acc[i][j]+bias[c];
      if (mode_out==1) v+=SE[r*128+c]+px[ty*4+i]*pwl[c*3]+py[ty*4+i]*pwl[c*3+1]+pz[ty*4+i]*pwl[c*3+2];
      C[r*128+c]=v;
    }
  }
}

__global__ __launch_bounds__(256) void kB2(const float* A1, float* A2, float* ws){
  int* iw=(int*)ws; float* fw=ws;
  int nf=iw[S_NF]; int n=iw[S_NINST];
  int r0=blockIdx.x*64;
  if (r0>=nf) return;
  __shared__ float kh[INST_MAX*128];
  __shared__ float vh[INST_MAX*128];
  __shared__ float ot[64][129];
  int t=threadIdx.x;
  for (int idx=t; idx<INST_MAX*128; idx+=256){
    kh[idx]=(idx<n*128)? fw[S_KHB+idx]:0.f;
    vh[idx]=(idx<n*128)? fw[S_VHB+idx]:0.f;
  }
  __syncthreads();
  int tokl=t&63, h=t>>6;
  int r=r0+tokl;
  bool valid=r<nf;
  float q[32];
  #pragma unroll
  for (int d=0;d<32;d++) q[d]=valid? A1[r*128+h*32+d]:0.f;
  float s[INST_MAX]; float mx=-1e30f;
  for (int j=0;j<INST_MAX;j++){
    float a=0.f;
    #pragma unroll
    for (int d=0;d<32;d++) a+=q[d]*kh[j*128+h*32+d];
    a*=RS32;
    s[j]=(j<n)? a:-1e30f;
    mx=fmaxf(mx,s[j]);
  }
  float sum=0.f;
  for (int j=0;j<INST_MAX;j++){ float p=expf(s[j]-mx); s[j]=p; sum+=p; }
  float inv=(n>0)? 1.0f/sum:0.f;
  float o[32];
  #pragma unroll
  for (int d=0;d<32;d++) o[d]=0.f;
  for (int j=0;j<INST_MAX;j++){
    float a=s[j]*inv;
    #pragma unroll
    for (int d=0;d<32;d++) o[d]+=a*vh[j*128+h*32+d];
  }
  #pragma unroll
  for (int d=0;d<32;d++) ot[tokl][h*32+d]=o[d];
  __syncthreads();
  for (int idx=t; idx<64*128; idx+=256){
    int rl=idx>>7, e=idx&127;
    if (r0+rl<nf) A2[(r0+rl)*128+e]=ot[rl][e];
  }
}

__global__ __launch_bounds__(256) void kLN(const float* A, float* B, const float* g, const float* b, float* ws){
  int* iw=(int*)ws;
  int nf=iw[S_NF];
  int t=threadIdx.x; int w=t>>6; int lane=t&63;
  int r=blockIdx.x*4+w;
  if (r>=nf) return;
  float v0=A[r*128+lane], v1=A[r*128+64+lane];
  float s=v0+v1;
  for (int o=32;o>0;o>>=1) s+=__shfl_xor(s,o);
  float mu=s*(1.0f/128.0f);
  float d0=v0-mu, d1=v1-mu;
  float vv=d0*d0+d1*d1;
  for (int o=32;o>0;o>>=1) vv+=__shfl_xor(vv,o);
  float rsv=rsqrtf(vv*(1.0f/128.0f)+1e-5f);
  B[r*128+lane]=d0*rsv*g[lane]+b[lane];
  B[r*128+64+lane]=d1*rsv*g[64+lane]+b[64+lane];
}

__global__ void k_transpose(const float* in, float* outp, int R, int C){
  __shared__ float tile[32][33];
  int bx=blockIdx.x*32, by=blockIdx.y*32;
  int tx=threadIdx.x, ty=threadIdx.y;
  for (int k=0;k<4;k++){
    int r=by+ty+k*8, c=bx+tx;
    if (r<R && c<C) tile[ty+k*8][tx]=in[(size_t)r*C+c];
  }
  __syncthreads();
  for (int k=0;k<4;k++){
    int cc=bx+ty+k*8, rr=by+tx;
    if (rr<R && cc<C) outp[(size_t)cc*R+rr]=tile[tx][ty+k*8];
  }
}

__global__ __launch_bounds__(256) void kFFN(const float* X_, float* SEo, const float* W1T, const float* W2T,
    const float* b1, const float* b2, const float* g, const float* bb, float* ws){
  int* iw=(int*)ws;
  int nf=iw[S_NF];
  int r0=blockIdx.x*16;
  if (r0>=nf) return;
  __shared__ float X[16][129];
  __shared__ float Hl[16][516];
  __shared__ float yl[16][129];
  int t=threadIdx.x;
  for (int idx=t; idx<16*128; idx+=256){
    int rl=idx>>7, e=idx&127;
    int r=r0+rl;
    X[rl][e]=(r<nf)? X_[r*128+e]:0.f;
  }
  __syncthreads();
  #pragma unroll
  for (int pass=0; pass<2; pass++){
    int d=t+pass*256;
    float acc[16];
    #pragma unroll
    for (int rl=0;rl<16;rl++) acc[rl]=0.f;
    for (int k=0;k<128;k++){
      float w=W1T[k*512+d];
      #pragma unroll
      for (int rl=0;rl<16;rl++) acc[rl]+=w*X[rl][k];
    }
    float bd=b1[d];
    #pragma unroll
    for (int rl=0;rl<16;rl++) Hl[rl][d]=fmaxf(acc[rl]+bd,0.f);
  }
  __syncthreads();
  {
    int e=t&127, g2=t>>7;
    float a2[8];
    #pragma unroll
    for (int rr=0;rr<8;rr++) a2[rr]=0.f;
    for (int d=0;d<512;d++){
      float w=W2T[d*128+e];
      #pragma unroll
      for (int rr=0;rr<8;rr++) a2[rr]+=w*Hl[g2*8+rr][d];
    }
    float be=b2[e];
    #pragma unroll
    for (int rr=0;rr<8;rr++){ int rl=g2*8+rr; yl[rl][e]=a2[rr]+be+X[rl][e]; }
  }
  __syncthreads();
  int w=t>>6, lane=t&63;
  for (int rl=w; rl<16; rl+=4){
    int r=r0+rl;
    float v0=yl[rl][lane], v1=yl[rl][64+lane];
    float s=v0+v1;
    for (int o=32;o>0;o>>=1) s+=__shfl_xor(s,o);
    float mu=s*(1.f/128.f);
    float d0=v0-mu, d1=v1-mu;
    float vv=d0*d0+d1*d1;
    for (int o=32;o>0;o>>=1) vv+=__shfl_xor(vv,o);
    float rsv=rsqrtf(vv*(1.f/128.f)+1e-5f);
    if (r<nf){
      SEo[r*128+lane]=d0*rsv*g[lane]+bb[lane];
      SEo[r*128+64+lane]=d1*rsv*g[64+lane]+bb[64+lane];
    }
  }
}

__global__ __launch_bounds__(256) void k_out(const float* SE, const float* sew, const float* x3d,
    const float* convw, const float* convb, const int* invr, float* out, float* ws){
  (void)ws;
  __shared__ float rows[64][129];
  __shared__ float cw[20*128];
  __shared__ float cb[20];
  __shared__ int rkl[64];
  int t=threadIdx.x;
  int q0=blockIdx.x*64;
  for (int idx=t; idx<20*128; idx+=256) cw[idx]=convw[idx];
  if (t<20) cb[t]=convb[t];
  if (t<64) rkl[t]=invr[q0+t];
  __syncthreads();
  for (int idx=t; idx<64*128; idx+=256){
    int v=idx>>7, e=idx&127;
    int rk=rkl[v];
    rows[v][e]=(rk>=0)? SE[rk*128+e]:sew[(size_t)(q0+v)*128+e];
  }
  __syncthreads();
  for (int idx=t; idx<128*64; idx+=256){
    int c=idx>>6, v=idx&63;
    if (rkl[v]<0) rows[v][c]+=x3d[(size_t)c*NQ+q0+v];
  }
  __syncthreads();
  int v=t&63;
  for (int o=t>>6; o<20; o+=4){
    float a=cb[o];
    const float* cr=cw+o*128;
    for (int c=0;c<128;c++) a+=rows[v][c]*cr[c];
    out[(size_t)o*NQ+q0+v]=a;
  }
}

extern "C" void kernel_launch(void* const* d_in, const int* in_sizes, int n_in,
                              void* d_out, int out_size, void* d_ws, size_t ws_size,
                              hipStream_t stream){
  (void)in_sizes; (void)n_in; (void)out_size; (void)ws_size;
  const float* queries  = (const float*)d_in[0];
  const float* plogits  = (const float*)d_in[1];
  const float* pmasks   = (const float*)d_in[2];
  const float* x3d      = (const float*)d_in[3];
  const float* depth    = (const float*)d_in[4];
  const float* Kmat     = (const float*)d_in[5];
  const float* Emat     = (const float*)d_in[6];
  const float* vorigin  = (const float*)d_in[7];
  const int*   fov      = (const int*)d_in[8];
  const float* sew      = (const float*)d_in[9];
  const float* instposw = (const float*)d_in[10];
  const float* posw     = (const float*)d_in[11];
  const float* convw    = (const float*)d_in[12];
  const float* convb    = (const float*)d_in[13];
  const float* AW       = (const float*)d_in[14];
  const float* AB       = (const float*)d_in[15];
  const float* LG       = (const float*)d_in[16];
  const float* LB       = (const float*)d_in[17];
  const float* F1W      = (const float*)d_in[18];
  const float* F1B      = (const float*)d_in[19];
  const float* F2W      = (const float*)d_in[20];
  const float* F2B      = (const float*)d_in[21];
  float* out = (float*)d_out;
  char* wsb = (char*)d_ws;
  float* fws = (float*)d_ws;
  int* fidx = (int*)(wsb + OFF_FIDX);
  int* invr = (int*)(wsb + OFF_INV);
  float* W1T = (float*)(wsb + OFF_W1T);
  float* W2T = (float*)(wsb + OFF_W2T);
  float* SE = (float*)(wsb + OFF_SE);
  float* A1 = (float*)(wsb + OFF_A1);
  float* A2 = (float*)(wsb + OFF_A2);
  float* SC = (float*)(wsb + OFF_SC);

  auto aw  = [&](int i,int br,int m){ return AW + (size_t)(((i*2+br)*4+m))*128*128; };
  auto ab  = [&](int i,int br,int m){ return AB + (size_t)(((i*2+br)*4+m))*128; };
  auto lng = [&](int i,int br,int wch){ return LG + (size_t)(((i*2+br)*2+wch))*128; };
  auto lnb = [&](int i,int br,int wch){ return LB + (size_t)(((i*2+br)*2+wch))*128; };
  auto f1w = [&](int i,int br){ return F1W + (size_t)(i*2+br)*512*128; };
  auto f1b = [&](int i,int br){ return F1B + (size_t)(i*2+br)*512; };
  auto f2w = [&](int i,int br){ return F2W + (size_t)(i*2+br)*128*512; };
  auto f2b = [&](int i,int br){ return F2B + (size_t)(i*2+br)*128; };

  const int NB64 = NF_MAX/64;   // 1152
  const int NB16 = NF_MAX/16;   // 4608
  const int NB4  = NF_MAX/4;    // 18432

  k_init<<<1,256,0,stream>>>(Kmat,Emat,fws);
  k_score<<<1,320,0,stream>>>(plogits,fws);
  k_winner<<<NPIX/256,256,0,stream>>>(pmasks,depth,fws);
  k_sel<<<1,256,0,stream>>>(queries,instposw,posw,fws);
  k_fov_count<<<256,256,0,stream>>>(fov,fws);
  k_fov_scan<<<1,64,0,stream>>>(fws);
  k_fov_scatter<<<256,256,0,stream>>>(fov,fws);
  k_se_build<<<NB64,256,0,stream>>>(sew,x3d,fidx,SE,fws);

  for (int i=0;i<2;i++){
    // ---- instance-side layer (queries = instances, keys/vals = scene) ----
    kA_prep<<<1,256,0,stream>>>(aw(i,0,0),ab(i,0,0),aw(i,0,1),ab(i,0,1),fws);
    kS1<<<NB64,256,0,stream>>>(SE,SC,posw,vorigin,fidx,fws);
    kS2S3<<<IH_MAX,256,0,stream>>>(SC,fws);
    kS4<<<256,256,0,stream>>>(SC,SE,fws);
    kA_post<<<1,256,0,stream>>>(aw(i,0,2),ab(i,0,2),aw(i,0,3),ab(i,0,3),lng(i,0,0),lnb(i,0,0),fws);
    kA_ffn<<<INST_MAX,256,0,stream>>>(f1w(i,0),f1b(i,0),f2w(i,0),f2b(i,0),lng(i,0,1),lnb(i,0,1),fws);
    kA_kv<<<1,256,0,stream>>>(aw(i,1,1),ab(i,1,1),aw(i,1,2),ab(i,1,2),fws);
    // ---- scene-side layer (queries = scene, keys/vals = instances) ----
    kGEMM<<<dim3(NB64,2),256,0,stream>>>(nullptr,A1,aw(i,1,0),ab(i,1,0),1,0,SE,fidx,posw,vorigin,fws);
    kB2<<<NB64,256,0,stream>>>(A1,A2,fws);
    kGEMM<<<dim3(NB64,2),256,0,stream>>>(A2,A1,aw(i,1,3),ab(i,1,3),0,1,SE,fidx,posw,vorigin,fws);
    kLN<<<NB4,256,0,stream>>>(A1,A2,lng(i,1,0),lnb(i,1,0),fws);
    k_transpose<<<dim3(4,16),dim3(32,8),0,stream>>>(f1w(i,1),W1T,512,128);
    k_transpose<<<dim3(16,4),dim3(32,8),0,stream>>>(f2w(i,1),W2T,128,512);
    kFFN<<<NB16,256,0,stream>>>(A2,SE,W1T,W2T,f1b(i,1),f2b(i,1),lng(i,1,1),lnb(i,1,1),fws);
  }
  k_out<<<NQ/64,256,0,stream>>>(SE,sew,x3d,convw,convb,invr,out,fws);
}